// Round 5
// baseline (155.775 us; speedup 1.0000x reference)
//
#include <hip/hip_runtime.h>
#include <hip/hip_fp16.h>

typedef _Float16 half8 __attribute__((ext_vector_type(8)));
typedef _Float16 half4v __attribute__((ext_vector_type(4)));
typedef float   float4v __attribute__((ext_vector_type(4)));
typedef float   float16v __attribute__((ext_vector_type(16)));

#define S_LEN 4096
#define NBATCH 4
#define NCHUNK 4
// ws layout in halves:
#define WS_W16 0
#define WS_QH  32768
#define WS_KH  1081344
#define WS_VT  2129920
#define WS_L   4227072    // float[16384] row sum-of-exp accumulators

// ---------------- kernel 0: weight convert + zero accumulators ----------------
__global__ __launch_bounds__(256) void prep_kernel(const float* __restrict__ Wq,
                                                   const float* __restrict__ Wk,
                                                   const float* __restrict__ Wv,
                                                   _Float16* __restrict__ w16,
                                                   float4v* __restrict__ out4,
                                                   float4v* __restrict__ l4) {
    int i = blockIdx.x * 256 + threadIdx.x;   // 0..524287
    if (i < 32768) {
        int row = i >> 7, col = i & 127;
        float v;
        if (row < 64)       v = Wq[row * 128 + col];
        else if (row < 128) v = Wk[(row - 64) * 128 + col];
        else                v = Wv[(row - 128) * 128 + col];
        w16[i] = (_Float16)v;
    }
    out4[i] = (float4v){0.f, 0.f, 0.f, 0.f};
    if (i < 4096) l4[i] = (float4v){0.f, 0.f, 0.f, 0.f};
}

// ---------------- kernel 1: QKV projection via MFMA ---------------------------
// grid 256 blocks x 256 thr; wave w owns token rows [w*16,+16), all 256 ocs.
// V routed through LDS so the transposed global write is coalesced.
__global__ __launch_bounds__(256) void qkv_proj_kernel(const float* __restrict__ x,
                                                       const _Float16* __restrict__ w16,
                                                       _Float16* __restrict__ Qh,
                                                       _Float16* __restrict__ Kh,
                                                       _Float16* __restrict__ Vt) {
    __shared__ _Float16 sh[128 * 72];   // phase 1: x-tile [64][136]; phase 2: V [128][72]
    const int t = threadIdx.x;
    const int blk = blockIdx.x;
    const float* xb = x + (size_t)blk * 64 * 128;

    for (int it = 0; it < 8; ++it) {
        int i = t + it * 256;           // 0..2047
        int row = i >> 5, c4 = i & 31;
        float4v f = ((const float4v*)xb)[i];
        half4v h;
        h[0] = (_Float16)f[0]; h[1] = (_Float16)f[1];
        h[2] = (_Float16)f[2]; h[3] = (_Float16)f[3];
        *(half4v*)&sh[row * 136 + c4 * 4] = h;
    }
    __syncthreads();

    const int w = t >> 6, lane = t & 63, quad = lane >> 4, n16 = lane & 15;

    half8 a[4];
    for (int c = 0; c < 4; ++c)
        a[c] = *(const half8*)&sh[(w * 16 + n16) * 136 + c * 32 + quad * 8];
    __syncthreads();   // x-tile fully read; sh reused for V below

    float4v acc[16];
    for (int nb = 0; nb < 16; ++nb) acc[nb] = (float4v){0.f, 0.f, 0.f, 0.f};

    for (int c = 0; c < 4; ++c) {
        for (int nb = 0; nb < 16; ++nb) {
            int oc = nb * 16 + n16;
            half8 bfr = *(const half8*)&w16[(size_t)oc * 128 + c * 32 + quad * 8];
            acc[nb] = __builtin_amdgcn_mfma_f32_16x16x32_f16(a[c], bfr, acc[nb], 0, 0, 0);
        }
    }

    const int token0 = blk * 64 + w * 16 + quad * 4;
    const int tok_l0 = w * 16 + quad * 4;
    for (int nb = 0; nb < 16; ++nb) {
        int oc = nb * 16 + n16;
        if (oc < 64) {
            for (int r = 0; r < 4; ++r)
                Qh[(size_t)(token0 + r) * 64 + oc] = (_Float16)acc[nb][r];
        } else if (oc < 128) {
            for (int r = 0; r < 4; ++r)
                Kh[(size_t)(token0 + r) * 64 + (oc - 64)] = (_Float16)acc[nb][r];
        } else {
            int vc = oc - 128;
            for (int r = 0; r < 4; ++r)
                sh[vc * 72 + tok_l0 + r] = (_Float16)acc[nb][r];
        }
    }
    __syncthreads();

    // coalesced V^T write-out: 128 rows x 64 tokens (128B per row)
    const int b = blk >> 6, s0 = (blk & 63) * 64;
    for (int it = 0; it < 4; ++it) {
        int i = t + it * 256;           // 0..1023
        int row = i >> 3, c8 = i & 7;
        *(half8*)&Vt[((size_t)b * 128 + row) * S_LEN + s0 + c8 * 8] =
            *(const half8*)&sh[row * 72 + c8 * 8];
    }
}

// ---------------- kernel 2: flash attention, 32x32 MFMA, K-split x4 -----------
// grid (S/64, NCHUNK, B), 128 threads (2 waves), 36KB LDS -> 4 blocks/CU.
// Wave w owns 32 q rows. Shifted-exp softmax: p = exp(s*0.125 - 4); partial
// (O, l) exactly additive across chunks -> fp32 HW atomics.
// 32x32x16 C/D layout (verified m74/m101): col=lane&31, row=(reg&3)+8*(reg>>2)+4*(lane>>5)
// A layout: m=lane&31, k=(lane>>5)*8+j ; B: n=lane&31, k=(lane>>5)*8+j
// R4 bug fixed here: with 128 threads, K staging needs 4 iters (512 x 16B) and
// V staging 8 iters (1024 x 16B); R4 kept R3's 256-thread trip counts, leaving
// half of Ks/Vs uninitialized -> NaN.
__global__ __launch_bounds__(128) void flash_kernel(const _Float16* __restrict__ Qh,
                                                    const _Float16* __restrict__ Kh,
                                                    const _Float16* __restrict__ Vt,
                                                    float* __restrict__ out,
                                                    float* __restrict__ lbuf) {
    __shared__ _Float16 Ks[64 * 72];        // K tile [64key][64ch]
    __shared__ _Float16 Vs[128 * 72];       // V^T tile [128ch][64key]
    __shared__ _Float16 Ps[2][32 * 72];     // per-wave P [32q][64key]

    const int t = threadIdx.x;
    const int qt = blockIdx.x, chunk = blockIdx.y, b = blockIdx.z;
    const int w = t >> 6, lane = t & 63, l32 = lane & 31, hi = lane >> 5;

    const size_t q0 = (size_t)b * S_LEN + qt * 64 + w * 32;
    half8 aQ[4];
    for (int ks = 0; ks < 4; ++ks)
        aQ[ks] = *(const half8*)&Qh[(q0 + l32) * 64 + ks * 16 + hi * 8];

    float16v O[4];
    for (int vb = 0; vb < 4; ++vb)
        for (int r = 0; r < 16; ++r) O[vb][r] = 0.f;
    float lsum[16];
    for (int r = 0; r < 16; ++r) lsum[r] = 0.f;

    const _Float16* Kb = Kh + (size_t)b * S_LEN * 64;
    const _Float16* Vb = Vt + (size_t)b * 128 * S_LEN;

    const int kt0 = chunk * (S_LEN / 64 / NCHUNK);
    const int kt1 = kt0 + (S_LEN / 64 / NCHUNK);

    half8 pK[4], pV[8];
    {   // prefetch first tile into regs
        const half8* srcK = (const half8*)(Kb + (size_t)kt0 * 64 * 64);
        for (int i = 0; i < 4; ++i) pK[i] = srcK[t + i * 128];
        for (int i = 0; i < 8; ++i) {
            int idx = t + i * 128, row = idx >> 3, c8 = idx & 7;
            pV[i] = *(const half8*)&Vb[(size_t)row * S_LEN + kt0 * 64 + c8 * 8];
        }
    }

    for (int kt = kt0; kt < kt1; ++kt) {
        __syncthreads();   // previous tile fully consumed
        for (int i = 0; i < 4; ++i) {
            int idx = t + i * 128, row = idx >> 3, c8 = idx & 7;
            *(half8*)&Ks[row * 72 + c8 * 8] = pK[i];
        }
        for (int i = 0; i < 8; ++i) {
            int idx = t + i * 128, row = idx >> 3, c8 = idx & 7;
            *(half8*)&Vs[row * 72 + c8 * 8] = pV[i];
        }
        __syncthreads();

        if (kt + 1 < kt1) {   // prefetch next tile; overlaps with compute below
            const half8* srcK = (const half8*)(Kb + (size_t)(kt + 1) * 64 * 64);
            for (int i = 0; i < 4; ++i) pK[i] = srcK[t + i * 128];
            for (int i = 0; i < 8; ++i) {
                int idx = t + i * 128, row = idx >> 3, c8 = idx & 7;
                pV[i] = *(const half8*)&Vb[(size_t)row * S_LEN + (kt + 1) * 64 + c8 * 8];
            }
        }

        // QK^T: S[32q x 64key] as 2 C-tiles
        for (int knb = 0; knb < 2; ++knb) {
            float16v S;
            for (int r = 0; r < 16; ++r) S[r] = 0.f;
            for (int ks = 0; ks < 4; ++ks) {
                half8 bK = *(const half8*)&Ks[(knb * 32 + l32) * 72 + ks * 16 + hi * 8];
                S = __builtin_amdgcn_mfma_f32_32x32x16_f16(aQ[ks], bK, S, 0, 0, 0);
            }
            for (int r = 0; r < 16; ++r) {
                float p = __expf(S[r] * 0.125f - 4.0f);
                lsum[r] += p;
                int row = (r & 3) + 8 * (r >> 2) + 4 * hi;
                Ps[w][row * 72 + knb * 32 + l32] = (_Float16)p;   // wave-private
            }
        }
        // ensure wave-private Ps writes complete before cross-lane re-read
        asm volatile("s_waitcnt lgkmcnt(0)" ::: "memory");

        // PV: O[32q x 128v] as 4 C-tiles
        half8 aP[4];
        for (int kb = 0; kb < 4; ++kb)
            aP[kb] = *(const half8*)&Ps[w][l32 * 72 + kb * 16 + hi * 8];
        for (int vb = 0; vb < 4; ++vb)
            for (int kb = 0; kb < 4; ++kb) {
                half8 bV = *(const half8*)&Vs[(vb * 32 + l32) * 72 + kb * 16 + hi * 8];
                O[vb] = __builtin_amdgcn_mfma_f32_32x32x16_f16(aP[kb], bV, O[vb], 0, 0, 0);
            }
    }

    // reduce row sums across the 32 col-lanes of each half-wave
    for (int m = 1; m < 32; m <<= 1)
        for (int r = 0; r < 16; ++r)
            lsum[r] += __shfl_xor(lsum[r], m);

    const int qbase = qt * 64 + w * 32;
    if (l32 == 0)
        for (int r = 0; r < 16; ++r) {
            int row = (r & 3) + 8 * (r >> 2) + 4 * hi;
            unsafeAtomicAdd(&lbuf[b * S_LEN + qbase + row], lsum[r]);
        }

    float* ob = out + ((size_t)b * S_LEN + qbase) * 128;
    for (int vb = 0; vb < 4; ++vb)
        for (int r = 0; r < 16; ++r) {
            int row = (r & 3) + 8 * (r >> 2) + 4 * hi;
            unsafeAtomicAdd(&ob[(size_t)row * 128 + vb * 32 + l32], O[vb][r]);
        }
}

// ---------------- kernel 3: normalize out by row sums -------------------------
__global__ __launch_bounds__(256) void norm_kernel(float4v* __restrict__ out4,
                                                   const float* __restrict__ lbuf) {
    int i = blockIdx.x * 256 + threadIdx.x;   // 0..524287 (32 float4 per row)
    float inv = 1.0f / lbuf[i >> 5];
    float4v v = out4[i];
    v[0] *= inv; v[1] *= inv; v[2] *= inv; v[3] *= inv;
    out4[i] = v;
}

// ---------------- launch ------------------------------------------------------
extern "C" void kernel_launch(void* const* d_in, const int* in_sizes, int n_in,
                              void* d_out, int out_size, void* d_ws, size_t ws_size,
                              hipStream_t stream) {
    const float* x  = (const float*)d_in[0];
    const float* Wq = (const float*)d_in[1];
    const float* Wk = (const float*)d_in[2];
    const float* Wv = (const float*)d_in[3];
    float* out = (float*)d_out;

    _Float16* ws = (_Float16*)d_ws;
    _Float16* w16 = ws + WS_W16;
    _Float16* Qh  = ws + WS_QH;
    _Float16* Kh  = ws + WS_KH;
    _Float16* Vt  = ws + WS_VT;
    float*    lbuf = (float*)(ws + WS_L);

    prep_kernel<<<2048, 256, 0, stream>>>(Wq, Wk, Wv, w16, (float4v*)out, (float4v*)lbuf);
    qkv_proj_kernel<<<NBATCH * S_LEN / 64, 256, 0, stream>>>(x, w16, Qh, Kh, Vt);
    flash_kernel<<<dim3(S_LEN / 64, NCHUNK, NBATCH), 128, 0, stream>>>(Qh, Kh, Vt, out, lbuf);
    norm_kernel<<<2048, 256, 0, stream>>>((float4v*)out, lbuf);
}